// Round 3
// baseline (386.062 us; speedup 1.0000x reference)
//
#include <hip/hip_runtime.h>

#define NGRAPH 256
#define NNODE  1000
#define NEDGE  16000
#define DIM    32
#define HSTR   20   // h row stride in floats (80B: 16B-aligned, spreads banks)

__device__ __forceinline__ unsigned monof(float f) {
  unsigned b = __float_as_uint(f);
  return (b & 0x80000000u) ? ~b : (b | 0x80000000u);
}

// exclusive block scan over 1024 threads; wsum = LDS[16]; leaves total in wsum[15]
__device__ __forceinline__ unsigned blockExclScan(unsigned v, unsigned* wsum, int tid) {
  __syncthreads();             // protect wsum from previous use
  int lane = tid & 63, w = tid >> 6;
  unsigned x = v;
  #pragma unroll
  for (int d = 1; d < 64; d <<= 1) {
    unsigned t = __shfl_up(x, d, 64);
    if (lane >= d) x += t;
  }
  if (lane == 63) wsum[w] = x;
  __syncthreads();
  if (w == 0) {
    unsigned s = (lane < 16) ? wsum[lane] : 0u;
    #pragma unroll
    for (int d = 1; d < 16; d <<= 1) {
      unsigned t = __shfl_up(s, d, 64);
      if (lane >= d) s += t;
    }
    if (lane < 16) wsum[lane] = s;
  }
  __syncthreads();
  unsigned base = (w > 0) ? wsum[w - 1] : 0u;
  return base + x - v;
}

__device__ __forceinline__ void max16(float* hv, const float* row) {
  const float4* hp = (const float4*)row;
  float4 a0 = hp[0], a1 = hp[1], a2 = hp[2], a3 = hp[3];
  hv[0]=fmaxf(hv[0],a0.x);  hv[1]=fmaxf(hv[1],a0.y);  hv[2]=fmaxf(hv[2],a0.z);  hv[3]=fmaxf(hv[3],a0.w);
  hv[4]=fmaxf(hv[4],a1.x);  hv[5]=fmaxf(hv[5],a1.y);  hv[6]=fmaxf(hv[6],a1.z);  hv[7]=fmaxf(hv[7],a1.w);
  hv[8]=fmaxf(hv[8],a2.x);  hv[9]=fmaxf(hv[9],a2.y);  hv[10]=fmaxf(hv[10],a2.z); hv[11]=fmaxf(hv[11],a2.w);
  hv[12]=fmaxf(hv[12],a3.x); hv[13]=fmaxf(hv[13],a3.y); hv[14]=fmaxf(hv[14],a3.z); hv[15]=fmaxf(hv[15],a3.w);
}

__device__ __forceinline__ void store16(float* row, const float* v) {
  float4* hp = (float4*)row;
  hp[0] = make_float4(v[0],v[1],v[2],v[3]);
  hp[1] = make_float4(v[4],v[5],v[6],v[7]);
  hp[2] = make_float4(v[8],v[9],v[10],v[11]);
  hp[3] = make_float4(v[12],v[13],v[14],v[15]);
}

__device__ __forceinline__ void loadscale16(float* v, const float* row, float s) {
  const float4* hp = (const float4*)row;
  float4 a0 = hp[0], a1 = hp[1], a2 = hp[2], a3 = hp[3];
  v[0]=a0.x*s;  v[1]=a0.y*s;  v[2]=a0.z*s;  v[3]=a0.w*s;
  v[4]=a1.x*s;  v[5]=a1.y*s;  v[6]=a1.z*s;  v[7]=a1.w*s;
  v[8]=a2.x*s;  v[9]=a2.y*s;  v[10]=a2.z*s; v[11]=a2.w*s;
  v[12]=a3.x*s; v[13]=a3.y*s; v[14]=a3.z*s; v[15]=a3.w*s;
}

extern "C" __global__ void __launch_bounds__(1024)
__attribute__((amdgpu_waves_per_eu(4, 4)))
gnn_topk_kernel(const int* __restrict__ x_ids, const int* __restrict__ eidx,
                const float* __restrict__ emb,
                const float* __restrict__ w1, const float* __restrict__ b1,
                const float* __restrict__ u1, const float* __restrict__ p1,
                const float* __restrict__ w2, const float* __restrict__ b2,
                const float* __restrict__ u2, const float* __restrict__ p2,
                const float* __restrict__ w3, const float* __restrict__ b3,
                const float* __restrict__ u3, const float* __restrict__ p3,
                const float* __restrict__ l1w, const float* __restrict__ l1b,
                const float* __restrict__ l2w, const float* __restrict__ l2b,
                const float* __restrict__ l3w, const float* __restrict__ l3b,
                float* __restrict__ out)
{
  const int g = blockIdx.x;
  const int tid = (int)threadIdx.x;
  const int lane = tid & 63, wv = tid >> 6;

  extern __shared__ unsigned char smem[];
  float* h_lds         = (float*)(smem);                      // 1000*20*4 = 80000
  unsigned short* csr  = (unsigned short*)(smem + 80000);     // 16000*2  = 32000
  unsigned* rowStart   = (unsigned*)(smem + 112000);          // 1001*4 -> 4016
  unsigned* cnt        = (unsigned*)(smem + 116016);          // 1024*4
  float* score         = (float*)(smem + 120112);             // 1024*4
  unsigned short* perm = (unsigned short*)(smem + 124208);    // 1024*2
  short* nidx          = (short*)(smem + 126256);             // 1024*2
  short* mp            = (short*)(smem + 128304);             // 1024*2
  unsigned* hist       = (unsigned*)(smem + 130352);          // 257*4 -> 1040
  unsigned* wsum       = (unsigned*)(smem + 131392);          // 16*4
  float* redm          = (float*)(smem + 131456);             // 16*32*4 = 2048
  float* reds          = (float*)(smem + 133504);             // 2048
  float* eacc          = (float*)(smem + 135552);             // 64*4
  float* hbuf          = (float*)(smem + 135808);             // 48*4 -> total 136000

  const int* esrc = eidx + (size_t)g * (2 * NEDGE);
  const int* edst = esrc + NEDGE;

  // ---- init: x = emb[ids] ----
  float x[DIM];
  if (tid < NNODE) {
    int id = x_ids[(size_t)g * NNODE + tid];
    const float4* ep = (const float4*)(emb + id * DIM);
    #pragma unroll
    for (int c4 = 0; c4 < 8; ++c4) {
      float4 v = ep[c4];
      x[c4*4+0]=v.x; x[c4*4+1]=v.y; x[c4*4+2]=v.z; x[c4*4+3]=v.w;
    }
  } else {
    #pragma unroll
    for (int c = 0; c < DIM; ++c) x[c] = 0.f;
  }
  mp[tid] = (tid < NNODE) ? (short)tid : (short)-1;
  if (tid < 64) eacc[tid] = 0.f;
  __syncthreads();

  int n = NNODE;
  #pragma unroll 1
  for (int layer = 0; layer < 3; ++layer) {
    const float* W  = (layer==0)? w1 : (layer==1)? w2 : w3;
    const float* Bv = (layer==0)? b1 : (layer==1)? b2 : b3;
    const float* U  = (layer==0)? u1 : (layer==1)? u2 : u3;
    const float* P  = (layer==0)? p1 : (layer==1)? p2 : p3;
    const int k     = (layer==0)? 800 : (layer==1)? 640 : 512;

    // ---- CSR build (group edges by current dst id) ----
    cnt[tid] = 0u;
    __syncthreads();
    for (int e = tid; e < NEDGE; e += 1024) {
      int s = mp[esrc[e]];
      int d = mp[edst[e]];
      if (s >= 0 && d >= 0) atomicAdd(&cnt[d], 1u);
    }
    __syncthreads();
    unsigned cv = cnt[tid];
    unsigned excl = blockExclScan(cv, wsum, tid);
    unsigned total = wsum[15];
    if (tid < n) rowStart[tid] = excl;
    if (tid == 0) rowStart[n] = total;
    cnt[tid] = excl;              // cursor (own slot only; no race)
    __syncthreads();
    for (int e = tid; e < NEDGE; e += 1024) {
      int s = mp[esrc[e]];
      int d = mp[edst[e]];
      if (s >= 0 && d >= 0) {
        unsigned pos = atomicAdd(&cnt[d], 1u);
        csr[pos] = (unsigned short)s;
      }
    }

    // ---- phase A: a0 = relu(W[0:16]@x + b[0:16]), store, aggregate, fold ----
    float a0[16];
    if (tid < n) {
      #pragma unroll
      for (int r = 0; r < 16; ++r) {
        float s = Bv[r];
        #pragma unroll
        for (int c = 0; c < DIM; ++c) s += W[r*32 + c] * x[c];
        a0[r] = fmaxf(s, 0.f);
      }
      store16(h_lds + tid * HSTR, a0);
    }
    __syncthreads();   // csr filled + h half0 visible
    float acc[DIM];
    if (tid < n) {
      unsigned beg = rowStart[tid], end = rowStart[tid+1];
      for (unsigned e = beg; e < end; ++e) {
        int s = csr[e];
        max16(a0, h_lds + s * HSTR);
      }
      #pragma unroll
      for (int r = 0; r < DIM; ++r) {
        float s = 0.f;
        #pragma unroll
        for (int c = 0; c < 16; ++c) s += U[r*64 + c] * a0[c];
        acc[r] = s;
      }
    }
    __syncthreads();
    // ---- phase B: a1 = relu(W[16:32]@x + b[16:32]), store, aggregate, finish ----
    float a1[16];
    if (tid < n) {
      #pragma unroll
      for (int r = 0; r < 16; ++r) {
        float s = Bv[16 + r];
        #pragma unroll
        for (int c = 0; c < DIM; ++c) s += W[(16+r)*32 + c] * x[c];
        a1[r] = fmaxf(s, 0.f);
      }
      store16(h_lds + tid * HSTR, a1);
    }
    __syncthreads();
    if (tid < n) {
      unsigned beg = rowStart[tid], end = rowStart[tid+1];
      for (unsigned e = beg; e < end; ++e) {
        int s = csr[e];
        max16(a1, h_lds + s * HSTR);
      }
      #pragma unroll
      for (int r = 0; r < DIM; ++r) {
        float s = acc[r];
        #pragma unroll
        for (int c = 0; c < 16; ++c) s += U[r*64 + 16 + c] * a1[c];
        #pragma unroll
        for (int c = 0; c < DIM; ++c) s += U[r*64 + 32 + c] * x[c];
        acc[r] = fmaxf(s, 0.f);
      }
      #pragma unroll
      for (int r = 0; r < DIM; ++r) x[r] = acc[r];   // new x
    }

    // ---- pool: score = tanh(x.p/||p||), exact top-k via radix select ----
    float pn = 0.f;
    #pragma unroll
    for (int c = 0; c < DIM; ++c) pn += P[c] * P[c];
    pn = sqrtf(pn);
    unsigned key = 0xFFFFFFFFu;
    if (tid < n) {
      float dp = 0.f;
      #pragma unroll
      for (int c = 0; c < DIM; ++c) dp += x[c] * P[c];
      float sc = tanhf(dp / pn);
      score[tid] = sc;
      key = ~monof(sc);   // ascending key == descending score
    }
    bool cand = (tid < n);
    bool sel = false;
    unsigned target = (unsigned)k;
    #pragma unroll 1
    for (int pass = 0; pass < 4; ++pass) {
      for (int i = tid; i < 257; i += 1024) hist[i] = 0u;
      __syncthreads();
      unsigned dig = (key >> (24 - 8*pass)) & 255u;
      if (cand) atomicAdd(&hist[dig], 1u);
      __syncthreads();
      if (tid < 64) {  // wave0: exclusive scan of 256 buckets
        unsigned a0s = hist[tid*4], a1s = hist[tid*4+1], a2s = hist[tid*4+2], a3s = hist[tid*4+3];
        unsigned s1 = a0s+a1s, s2v = s1+a2s, s3 = s2v+a3s;
        unsigned tot = s3;
        #pragma unroll
        for (int d = 1; d < 64; d <<= 1) {
          unsigned t = __shfl_up(tot, d, 64);
          if (lane >= d) tot += t;
        }
        unsigned base = tot - s3;
        hist[tid*4] = base; hist[tid*4+1] = base+a0s; hist[tid*4+2] = base+s1; hist[tid*4+3] = base+s2v;
        if (tid == 63) hist[256] = tot;
      }
      __syncthreads();
      if (cand) {
        unsigned lo = hist[dig], hi = hist[dig+1];
        if (hi <= target)      { sel = true;  cand = false; }
        else if (lo >= target) { cand = false; }
        else                   { target -= lo; }
      }
      __syncthreads();
    }
    // tie resolution among pivot-equal candidates: smallest indices win
    unsigned trank = blockExclScan(cand ? 1u : 0u, wsum, tid);
    if (cand && trank < target) sel = true;
    unsigned pos = blockExclScan(sel ? 1u : 0u, wsum, tid);
    nidx[tid] = -1;
    __syncthreads();
    if (sel) { nidx[tid] = (short)pos; perm[pos] = (unsigned short)tid; }
    __syncthreads();

    // ---- gather xn = x[perm]*vals through LDS (2 halves) ----
    if (tid < n) store16(h_lds + tid * HSTR, x);
    __syncthreads();
    float nx0[16]; float val = 0.f; int pj = 0;
    if (tid < k) {
      pj = perm[tid];
      val = score[pj];
      loadscale16(nx0, h_lds + pj * HSTR, val);
    }
    __syncthreads();
    if (tid < n) {
      float4* hp = (float4*)(h_lds + tid * HSTR);
      hp[0] = make_float4(x[16],x[17],x[18],x[19]);
      hp[1] = make_float4(x[20],x[21],x[22],x[23]);
      hp[2] = make_float4(x[24],x[25],x[26],x[27]);
      hp[3] = make_float4(x[28],x[29],x[30],x[31]);
    }
    __syncthreads();
    if (tid < k) {
      float nx1[16];
      loadscale16(nx1, h_lds + pj * HSTR, val);
      #pragma unroll
      for (int c = 0; c < 16; ++c) { x[c] = nx0[c]; x[16+c] = nx1[c]; }
    } else {
      #pragma unroll
      for (int c = 0; c < DIM; ++c) x[c] = 0.f;
    }
    // compose orig->current map
    {
      short m0 = mp[tid];
      if (m0 >= 0) mp[tid] = nidx[m0];
    }
    n = k;

    // ---- readout: gmp || gap on pooled x, accumulate into eacc ----
    #pragma unroll
    for (int ch = 0; ch < 2; ++ch) {
      float mx[16], sm[16];
      #pragma unroll
      for (int f = 0; f < 16; ++f) {
        float v = x[ch*16+f];
        bool act = (tid < n);
        mx[f] = act ? v : -__builtin_inff();
        sm[f] = act ? v : 0.f;
      }
      #pragma unroll
      for (int d = 32; d >= 1; d >>= 1) {
        #pragma unroll
        for (int f = 0; f < 16; ++f) {
          mx[f] = fmaxf(mx[f], __shfl_xor(mx[f], d, 64));
          sm[f] += __shfl_xor(sm[f], d, 64);
        }
      }
      if (lane == 0) {
        #pragma unroll
        for (int f = 0; f < 16; ++f) {
          redm[wv*32 + ch*16 + f] = mx[f];
          reds[wv*32 + ch*16 + f] = sm[f];
        }
      }
    }
    __syncthreads();
    if (tid < 32) {
      float rm = -__builtin_inff(), rs = 0.f;
      #pragma unroll
      for (int w_ = 0; w_ < 16; ++w_) {
        rm = fmaxf(rm, redm[w_*32 + tid]);
        rs += reds[w_*32 + tid];
      }
      eacc[tid] += rm;
      eacc[32 + tid] += rs / (float)n;
    }
    __syncthreads();
  }

  // ---- MLP head ----
  if (tid < 32) {
    float v = l1b[tid];
    #pragma unroll
    for (int c = 0; c < 64; ++c) v += l1w[tid*64 + c] * eacc[c];
    hbuf[tid] = fmaxf(v, 0.f);
  }
  __syncthreads();
  if (tid < 16) {
    float v = l2b[tid];
    #pragma unroll
    for (int c = 0; c < 32; ++c) v += l2w[tid*32 + c] * hbuf[c];
    hbuf[32 + tid] = fmaxf(v, 0.f);
  }
  __syncthreads();
  if (tid == 0) {
    float v = l3b[0];
    #pragma unroll
    for (int c = 0; c < 16; ++c) v += l3w[c] * hbuf[32 + c];
    out[g] = 1.f / (1.f + expf(-v));
  }
  if (tid < 64) out[NGRAPH + (size_t)g*64 + tid] = eacc[tid];
}

extern "C" void kernel_launch(void* const* d_in, const int* in_sizes, int n_in,
                              void* d_out, int out_size, void* d_ws, size_t ws_size,
                              hipStream_t stream) {
  (void)in_sizes; (void)n_in; (void)d_ws; (void)ws_size; (void)out_size;
  const int*   x_ids = (const int*)d_in[0];
  const int*   eidx  = (const int*)d_in[1];
  const float* emb   = (const float*)d_in[2];
  const float* w1 = (const float*)d_in[3],  *b1 = (const float*)d_in[4];
  const float* u1 = (const float*)d_in[5],  *p1 = (const float*)d_in[6];
  const float* w2 = (const float*)d_in[7],  *b2 = (const float*)d_in[8];
  const float* u2 = (const float*)d_in[9],  *p2 = (const float*)d_in[10];
  const float* w3 = (const float*)d_in[11], *b3 = (const float*)d_in[12];
  const float* u3 = (const float*)d_in[13], *p3 = (const float*)d_in[14];
  const float* l1w = (const float*)d_in[15], *l1b = (const float*)d_in[16];
  const float* l2w = (const float*)d_in[17], *l2b = (const float*)d_in[18];
  const float* l3w = (const float*)d_in[19], *l3b = (const float*)d_in[20];
  float* out = (float*)d_out;

  gnn_topk_kernel<<<dim3(NGRAPH), dim3(1024), 136000, stream>>>(
      x_ids, eidx, emb,
      w1, b1, u1, p1, w2, b2, u2, p2, w3, b3, u3, p3,
      l1w, l1b, l2w, l2b, l3w, l3b, out);
}

// Round 4
// 345.113 us; speedup vs baseline: 1.1187x; 1.1187x over previous
//
#include <hip/hip_runtime.h>

#define NGRAPH 256
#define NNODE  1000
#define NEDGE  16000
#define DIM    32
#define HSTR   20   // h row stride in floats (80B: 16B-aligned, spreads banks)

#if __has_attribute(amdgpu_num_vgpr)
#define VGPR_ATTR __attribute__((amdgpu_num_vgpr(128)))
#else
#define VGPR_ATTR
#endif

__device__ __forceinline__ unsigned monof(float f) {
  unsigned b = __float_as_uint(f);
  return (b & 0x80000000u) ? ~b : (b | 0x80000000u);
}

// exclusive block scan over 1024 threads; wsum = LDS[16]; leaves total in wsum[15]
__device__ __forceinline__ unsigned blockExclScan(unsigned v, unsigned* wsum, int tid) {
  __syncthreads();             // protect wsum from previous use
  int lane = tid & 63, w = tid >> 6;
  unsigned x = v;
  #pragma unroll
  for (int d = 1; d < 64; d <<= 1) {
    unsigned t = __shfl_up(x, d, 64);
    if (lane >= d) x += t;
  }
  if (lane == 63) wsum[w] = x;
  __syncthreads();
  if (w == 0) {
    unsigned s = (lane < 16) ? wsum[lane] : 0u;
    #pragma unroll
    for (int d = 1; d < 16; d <<= 1) {
      unsigned t = __shfl_up(s, d, 64);
      if (lane >= d) s += t;
    }
    if (lane < 16) wsum[lane] = s;
  }
  __syncthreads();
  unsigned base = (w > 0) ? wsum[w - 1] : 0u;
  return base + x - v;
}

__device__ __forceinline__ void max16(float* hv, const float* row) {
  const float4* hp = (const float4*)row;
  float4 a0 = hp[0], a1 = hp[1], a2 = hp[2], a3 = hp[3];
  hv[0]=fmaxf(hv[0],a0.x);  hv[1]=fmaxf(hv[1],a0.y);  hv[2]=fmaxf(hv[2],a0.z);  hv[3]=fmaxf(hv[3],a0.w);
  hv[4]=fmaxf(hv[4],a1.x);  hv[5]=fmaxf(hv[5],a1.y);  hv[6]=fmaxf(hv[6],a1.z);  hv[7]=fmaxf(hv[7],a1.w);
  hv[8]=fmaxf(hv[8],a2.x);  hv[9]=fmaxf(hv[9],a2.y);  hv[10]=fmaxf(hv[10],a2.z); hv[11]=fmaxf(hv[11],a2.w);
  hv[12]=fmaxf(hv[12],a3.x); hv[13]=fmaxf(hv[13],a3.y); hv[14]=fmaxf(hv[14],a3.z); hv[15]=fmaxf(hv[15],a3.w);
}

__device__ __forceinline__ void store16(float* row, const float* v) {
  float4* hp = (float4*)row;
  hp[0] = make_float4(v[0],v[1],v[2],v[3]);
  hp[1] = make_float4(v[4],v[5],v[6],v[7]);
  hp[2] = make_float4(v[8],v[9],v[10],v[11]);
  hp[3] = make_float4(v[12],v[13],v[14],v[15]);
}

__device__ __forceinline__ void loadscale16(float* v, const float* row, float s) {
  const float4* hp = (const float4*)row;
  float4 a0 = hp[0], a1 = hp[1], a2 = hp[2], a3 = hp[3];
  v[0]=a0.x*s;  v[1]=a0.y*s;  v[2]=a0.z*s;  v[3]=a0.w*s;
  v[4]=a1.x*s;  v[5]=a1.y*s;  v[6]=a1.z*s;  v[7]=a1.w*s;
  v[8]=a2.x*s;  v[9]=a2.y*s;  v[10]=a2.z*s; v[11]=a2.w*s;
  v[12]=a3.x*s; v[13]=a3.y*s; v[14]=a3.z*s; v[15]=a3.w*s;
}

extern "C" __global__ void __launch_bounds__(1024)
__attribute__((amdgpu_waves_per_eu(4, 4))) VGPR_ATTR
gnn_topk_kernel(const int* __restrict__ x_ids, const int* __restrict__ eidx,
                const float* __restrict__ emb,
                const float* __restrict__ w1, const float* __restrict__ b1,
                const float* __restrict__ u1, const float* __restrict__ p1,
                const float* __restrict__ w2, const float* __restrict__ b2,
                const float* __restrict__ u2, const float* __restrict__ p2,
                const float* __restrict__ w3, const float* __restrict__ b3,
                const float* __restrict__ u3, const float* __restrict__ p3,
                const float* __restrict__ l1w, const float* __restrict__ l1b,
                const float* __restrict__ l2w, const float* __restrict__ l2b,
                const float* __restrict__ l3w, const float* __restrict__ l3b,
                float* __restrict__ out)
{
  const int g = blockIdx.x;
  const int tid = (int)threadIdx.x;
  const int lane = tid & 63, wv = tid >> 6;

  extern __shared__ unsigned char smem[];
  float* h_lds         = (float*)(smem);                      // 1000*20*4 = 80000
  unsigned* stage      = (unsigned*)(smem);                   // 16000*4 = 64000 (aliases h_lds; disjoint in time)
  unsigned short* csr  = (unsigned short*)(smem + 80000);     // 16000*2  = 32000
  unsigned* rowStart   = (unsigned*)(smem + 112000);          // 1001*4 -> 4016
  unsigned* cnt        = (unsigned*)(smem + 116016);          // 1024*4
  float* score         = (float*)(smem + 120112);             // 1024*4
  unsigned short* perm = (unsigned short*)(smem + 124208);    // 1024*2
  short* nidx          = (short*)(smem + 126256);             // 1024*2
  short* mp            = (short*)(smem + 128304);             // 1024*2
  unsigned* hist       = (unsigned*)(smem + 130352);          // 257*4 -> 1040
  unsigned* wsum       = (unsigned*)(smem + 131392);          // 16*4
  float* redm          = (float*)(smem + 131456);             // 16*32*4 = 2048
  float* reds          = (float*)(smem + 133504);             // 2048
  float* eacc          = (float*)(smem + 135552);             // 64*4
  float* hbuf          = (float*)(smem + 135808);             // 48*4 -> total 136000

  const int* esrc = eidx + (size_t)g * (2 * NEDGE);
  const int* edst = esrc + NEDGE;

  // ---- init: x = emb[ids] ----
  float x[DIM];
  if (tid < NNODE) {
    int id = x_ids[(size_t)g * NNODE + tid];
    const float4* ep = (const float4*)(emb + id * DIM);
    #pragma unroll
    for (int c4 = 0; c4 < 8; ++c4) {
      float4 v = ep[c4];
      x[c4*4+0]=v.x; x[c4*4+1]=v.y; x[c4*4+2]=v.z; x[c4*4+3]=v.w;
    }
  } else {
    #pragma unroll
    for (int c = 0; c < DIM; ++c) x[c] = 0.f;
  }
  mp[tid] = (tid < NNODE) ? (short)tid : (short)-1;
  if (tid < 64) eacc[tid] = 0.f;
  __syncthreads();

  int n = NNODE;
  #pragma unroll 1
  for (int layer = 0; layer < 3; ++layer) {
    const float* W  = (layer==0)? w1 : (layer==1)? w2 : w3;
    const float* Bv = (layer==0)? b1 : (layer==1)? b2 : b3;
    const float* U  = (layer==0)? u1 : (layer==1)? u2 : u3;
    const float* P  = (layer==0)? p1 : (layer==1)? p2 : p3;
    const int k     = (layer==0)? 800 : (layer==1)? 640 : 512;

    // ---- CSR build: single global edge pass, stage mapped pairs in LDS ----
    cnt[tid] = 0u;
    __syncthreads();
    for (int e = tid; e < NEDGE; e += 1024) {
      int s = mp[esrc[e]];
      int d = mp[edst[e]];
      unsigned pk = 0xFFFFFFFFu;
      if (s >= 0 && d >= 0) {
        pk = ((unsigned)d << 16) | (unsigned)s;
        atomicAdd(&cnt[d], 1u);
      }
      stage[e] = pk;
    }
    __syncthreads();
    unsigned cv = cnt[tid];
    unsigned excl = blockExclScan(cv, wsum, tid);
    unsigned total = wsum[15];
    if (tid < n) rowStart[tid] = excl;
    if (tid == 0) rowStart[n] = total;
    cnt[tid] = excl;              // cursor
    __syncthreads();
    for (int e = tid; e < NEDGE; e += 1024) {
      unsigned pk = stage[e];
      if (pk != 0xFFFFFFFFu) {
        unsigned d = pk >> 16;
        unsigned pos = atomicAdd(&cnt[d], 1u);
        csr[pos] = (unsigned short)(pk & 0xFFFFu);
      }
    }
    __syncthreads();   // stage fully consumed; csr complete; h_lds free to reuse

    // ---- per-node matmuls: acc = U[:,32:64] @ x ; h = relu(W x + b) ----
    float acc[DIM], hv0[16], hv1[16];
    if (tid < n) {
      #pragma unroll
      for (int r = 0; r < DIM; ++r) {
        float s = 0.f;
        #pragma unroll
        for (int c = 0; c < DIM; ++c) s += U[r*64 + 32 + c] * x[c];
        acc[r] = s;
      }
      #pragma unroll
      for (int r = 0; r < 16; ++r) {
        float s = Bv[r];
        #pragma unroll
        for (int c = 0; c < DIM; ++c) s += W[r*32 + c] * x[c];
        hv0[r] = fmaxf(s, 0.f);
      }
      #pragma unroll
      for (int r = 0; r < 16; ++r) {
        float s = Bv[16 + r];
        #pragma unroll
        for (int c = 0; c < DIM; ++c) s += W[(16+r)*32 + c] * x[c];
        hv1[r] = fmaxf(s, 0.f);
      }
      store16(h_lds + tid * HSTR, hv0);
    }
    __syncthreads();   // h half0 visible

    // ---- aggregate half0 (self-loop = init with own hv0) ----
    if (tid < n) {
      unsigned beg = rowStart[tid], end = rowStart[tid+1];
      for (unsigned e = beg; e < end; ++e) {
        int s = csr[e];
        max16(hv0, h_lds + s * HSTR);
      }
      #pragma unroll
      for (int r = 0; r < DIM; ++r) {
        float s = acc[r];
        #pragma unroll
        for (int c = 0; c < 16; ++c) s += U[r*64 + c] * hv0[c];
        acc[r] = s;
      }
    }
    __syncthreads();
    if (tid < n) store16(h_lds + tid * HSTR, hv1);
    __syncthreads();
    // ---- aggregate half1 + finish out = relu(U @ [aggr|x]) ----
    if (tid < n) {
      unsigned beg = rowStart[tid], end = rowStart[tid+1];
      for (unsigned e = beg; e < end; ++e) {
        int s = csr[e];
        max16(hv1, h_lds + s * HSTR);
      }
      #pragma unroll
      for (int r = 0; r < DIM; ++r) {
        float s = acc[r];
        #pragma unroll
        for (int c = 0; c < 16; ++c) s += U[r*64 + 16 + c] * hv1[c];
        x[r] = fmaxf(s, 0.f);   // new x
      }
    }

    // ---- pool: score = tanh(x.p/||p||), exact top-k via radix select ----
    float pn = 0.f;
    #pragma unroll
    for (int c = 0; c < DIM; ++c) pn += P[c] * P[c];
    pn = sqrtf(pn);
    unsigned key = 0xFFFFFFFFu;
    if (tid < n) {
      float dp = 0.f;
      #pragma unroll
      for (int c = 0; c < DIM; ++c) dp += x[c] * P[c];
      float sc = tanhf(dp / pn);
      score[tid] = sc;
      key = ~monof(sc);   // ascending key == descending score
    }
    bool cand = (tid < n);
    bool sel = false;
    unsigned target = (unsigned)k;
    #pragma unroll 1
    for (int pass = 0; pass < 4; ++pass) {
      for (int i = tid; i < 257; i += 1024) hist[i] = 0u;
      __syncthreads();
      unsigned dig = (key >> (24 - 8*pass)) & 255u;
      if (cand) atomicAdd(&hist[dig], 1u);
      __syncthreads();
      if (tid < 64) {  // wave0: exclusive scan of 256 buckets
        unsigned a0s = hist[tid*4], a1s = hist[tid*4+1], a2s = hist[tid*4+2], a3s = hist[tid*4+3];
        unsigned s1 = a0s+a1s, s2v = s1+a2s, s3 = s2v+a3s;
        unsigned tot = s3;
        #pragma unroll
        for (int d = 1; d < 64; d <<= 1) {
          unsigned t = __shfl_up(tot, d, 64);
          if (lane >= d) tot += t;
        }
        unsigned base = tot - s3;
        hist[tid*4] = base; hist[tid*4+1] = base+a0s; hist[tid*4+2] = base+s1; hist[tid*4+3] = base+s2v;
        if (tid == 63) hist[256] = tot;
      }
      __syncthreads();
      if (cand) {
        unsigned lo = hist[dig], hi = hist[dig+1];
        if (hi <= target)      { sel = true;  cand = false; }
        else if (lo >= target) { cand = false; }
        else                   { target -= lo; }
      }
      __syncthreads();
    }
    // tie resolution among pivot-equal candidates: smallest indices win
    unsigned trank = blockExclScan(cand ? 1u : 0u, wsum, tid);
    if (cand && trank < target) sel = true;
    unsigned pos = blockExclScan(sel ? 1u : 0u, wsum, tid);
    nidx[tid] = -1;
    __syncthreads();
    if (sel) { nidx[tid] = (short)pos; perm[pos] = (unsigned short)tid; }
    __syncthreads();

    // ---- gather xn = x[perm]*vals through LDS (2 halves) ----
    if (tid < n) store16(h_lds + tid * HSTR, x);
    __syncthreads();
    float nx0[16]; float val = 0.f; int pj = 0;
    if (tid < k) {
      pj = perm[tid];
      val = score[pj];
      loadscale16(nx0, h_lds + pj * HSTR, val);
    }
    __syncthreads();
    if (tid < n) {
      float4* hp = (float4*)(h_lds + tid * HSTR);
      hp[0] = make_float4(x[16],x[17],x[18],x[19]);
      hp[1] = make_float4(x[20],x[21],x[22],x[23]);
      hp[2] = make_float4(x[24],x[25],x[26],x[27]);
      hp[3] = make_float4(x[28],x[29],x[30],x[31]);
    }
    __syncthreads();
    if (tid < k) {
      float nx1[16];
      loadscale16(nx1, h_lds + pj * HSTR, val);
      #pragma unroll
      for (int c = 0; c < 16; ++c) { x[c] = nx0[c]; x[16+c] = nx1[c]; }
    } else {
      #pragma unroll
      for (int c = 0; c < DIM; ++c) x[c] = 0.f;
    }
    // compose orig->current map
    {
      short m0 = mp[tid];
      if (m0 >= 0) mp[tid] = nidx[m0];
    }
    n = k;

    // ---- readout: gmp || gap on pooled x, accumulate into eacc ----
    #pragma unroll
    for (int ch = 0; ch < 2; ++ch) {
      float mx[16], sm[16];
      #pragma unroll
      for (int f = 0; f < 16; ++f) {
        float v = x[ch*16+f];
        bool act = (tid < n);
        mx[f] = act ? v : -__builtin_inff();
        sm[f] = act ? v : 0.f;
      }
      #pragma unroll
      for (int d = 32; d >= 1; d >>= 1) {
        #pragma unroll
        for (int f = 0; f < 16; ++f) {
          mx[f] = fmaxf(mx[f], __shfl_xor(mx[f], d, 64));
          sm[f] += __shfl_xor(sm[f], d, 64);
        }
      }
      if (lane == 0) {
        #pragma unroll
        for (int f = 0; f < 16; ++f) {
          redm[wv*32 + ch*16 + f] = mx[f];
          reds[wv*32 + ch*16 + f] = sm[f];
        }
      }
    }
    __syncthreads();
    if (tid < 32) {
      float rm = -__builtin_inff(), rs = 0.f;
      #pragma unroll
      for (int w_ = 0; w_ < 16; ++w_) {
        rm = fmaxf(rm, redm[w_*32 + tid]);
        rs += reds[w_*32 + tid];
      }
      eacc[tid] += rm;
      eacc[32 + tid] += rs / (float)n;
    }
    __syncthreads();
  }

  // ---- MLP head ----
  if (tid < 32) {
    float v = l1b[tid];
    #pragma unroll
    for (int c = 0; c < 64; ++c) v += l1w[tid*64 + c] * eacc[c];
    hbuf[tid] = fmaxf(v, 0.f);
  }
  __syncthreads();
  if (tid < 16) {
    float v = l2b[tid];
    #pragma unroll
    for (int c = 0; c < 32; ++c) v += l2w[tid*32 + c] * hbuf[c];
    hbuf[32 + tid] = fmaxf(v, 0.f);
  }
  __syncthreads();
  if (tid == 0) {
    float v = l3b[0];
    #pragma unroll
    for (int c = 0; c < 16; ++c) v += l3w[c] * hbuf[32 + c];
    out[g] = 1.f / (1.f + expf(-v));
  }
  if (tid < 64) out[NGRAPH + (size_t)g*64 + tid] = eacc[tid];
}

extern "C" void kernel_launch(void* const* d_in, const int* in_sizes, int n_in,
                              void* d_out, int out_size, void* d_ws, size_t ws_size,
                              hipStream_t stream) {
  (void)in_sizes; (void)n_in; (void)d_ws; (void)ws_size; (void)out_size;
  const int*   x_ids = (const int*)d_in[0];
  const int*   eidx  = (const int*)d_in[1];
  const float* emb   = (const float*)d_in[2];
  const float* w1 = (const float*)d_in[3],  *b1 = (const float*)d_in[4];
  const float* u1 = (const float*)d_in[5],  *p1 = (const float*)d_in[6];
  const float* w2 = (const float*)d_in[7],  *b2 = (const float*)d_in[8];
  const float* u2 = (const float*)d_in[9],  *p2 = (const float*)d_in[10];
  const float* w3 = (const float*)d_in[11], *b3 = (const float*)d_in[12];
  const float* u3 = (const float*)d_in[13], *p3 = (const float*)d_in[14];
  const float* l1w = (const float*)d_in[15], *l1b = (const float*)d_in[16];
  const float* l2w = (const float*)d_in[17], *l2b = (const float*)d_in[18];
  const float* l3w = (const float*)d_in[19], *l3b = (const float*)d_in[20];
  float* out = (float*)d_out;

  gnn_topk_kernel<<<dim3(NGRAPH), dim3(1024), 136000, stream>>>(
      x_ids, eidx, emb,
      w1, b1, u1, p1, w2, b2, u2, p2, w3, b3, u3, p3,
      l1w, l1b, l2w, l2b, l3w, l3b, out);
}

// Round 5
// 343.669 us; speedup vs baseline: 1.1234x; 1.0042x over previous
//
#include <hip/hip_runtime.h>

#define NGRAPH 256
#define NNODE  1000
#define NEDGE  16000
#define DIM    32
#define HSTR   20   // h row stride in floats (80B: 16B-aligned, spreads banks)

__device__ __forceinline__ unsigned monof(float f) {
  unsigned b = __float_as_uint(f);
  return (b & 0x80000000u) ? ~b : (b | 0x80000000u);
}

struct Smem {
  union { float h[NNODE * HSTR]; unsigned stage[NEDGE]; } hu;  // 80000 B
  unsigned short csr[NEDGE];      // 32000
  unsigned rowStart[NNODE + 1];   // 4004
  unsigned cnt[1024];             // 4096
  float score[1024];              // 4096
  unsigned short perm[1024];      // 2048
  short nidx[1024];               // 2048
  short mp[1024];                 // 2048
  unsigned hist[257];             // 1028
  unsigned wsum[16];              // 64
  float redm[512];                // 2048
  float reds[512];                // 2048
  float eacc[64];                 // 256
  float hbuf[48];                 // 192  => ~136 KB total
};

// exclusive block scan over 1024 threads; leaves total in wsum[15]
__device__ __forceinline__ unsigned blockExclScan(unsigned v, unsigned* wsum, int tid) {
  __syncthreads();             // protect wsum from previous use
  int lane = tid & 63, w = tid >> 6;
  unsigned x = v;
  #pragma unroll
  for (int d = 1; d < 64; d <<= 1) {
    unsigned t = __shfl_up(x, d, 64);
    if (lane >= d) x += t;
  }
  if (lane == 63) wsum[w] = x;
  __syncthreads();
  if (w == 0) {
    unsigned s = (lane < 16) ? wsum[lane] : 0u;
    #pragma unroll
    for (int d = 1; d < 16; d <<= 1) {
      unsigned t = __shfl_up(s, d, 64);
      if (lane >= d) s += t;
    }
    if (lane < 16) wsum[lane] = s;
  }
  __syncthreads();
  unsigned base = (w > 0) ? wsum[w - 1] : 0u;
  return base + x - v;
}

__device__ __forceinline__ void max16(float* hv, const float* row) {
  const float4* hp = (const float4*)row;
  float4 a0 = hp[0], a1 = hp[1], a2 = hp[2], a3 = hp[3];
  hv[0]=fmaxf(hv[0],a0.x);  hv[1]=fmaxf(hv[1],a0.y);  hv[2]=fmaxf(hv[2],a0.z);  hv[3]=fmaxf(hv[3],a0.w);
  hv[4]=fmaxf(hv[4],a1.x);  hv[5]=fmaxf(hv[5],a1.y);  hv[6]=fmaxf(hv[6],a1.z);  hv[7]=fmaxf(hv[7],a1.w);
  hv[8]=fmaxf(hv[8],a2.x);  hv[9]=fmaxf(hv[9],a2.y);  hv[10]=fmaxf(hv[10],a2.z); hv[11]=fmaxf(hv[11],a2.w);
  hv[12]=fmaxf(hv[12],a3.x); hv[13]=fmaxf(hv[13],a3.y); hv[14]=fmaxf(hv[14],a3.z); hv[15]=fmaxf(hv[15],a3.w);
}

__device__ __forceinline__ void store16(float* row, const float* v) {
  float4* hp = (float4*)row;
  hp[0] = make_float4(v[0],v[1],v[2],v[3]);
  hp[1] = make_float4(v[4],v[5],v[6],v[7]);
  hp[2] = make_float4(v[8],v[9],v[10],v[11]);
  hp[3] = make_float4(v[12],v[13],v[14],v[15]);
}

__device__ __forceinline__ void loadscale16(float* v, const float* row, float s) {
  const float4* hp = (const float4*)row;
  float4 a0 = hp[0], a1 = hp[1], a2 = hp[2], a3 = hp[3];
  v[0]=a0.x*s;  v[1]=a0.y*s;  v[2]=a0.z*s;  v[3]=a0.w*s;
  v[4]=a1.x*s;  v[5]=a1.y*s;  v[6]=a1.z*s;  v[7]=a1.w*s;
  v[8]=a2.x*s;  v[9]=a2.y*s;  v[10]=a2.z*s; v[11]=a2.w*s;
  v[12]=a3.x*s; v[13]=a3.y*s; v[14]=a3.z*s; v[15]=a3.w*s;
}

extern "C" __global__ void __launch_bounds__(1024)
__attribute__((amdgpu_waves_per_eu(4, 4)))
gnn_topk_kernel(const int* __restrict__ x_ids, const int* __restrict__ eidx,
                const float* __restrict__ emb,
                const float* __restrict__ w1, const float* __restrict__ b1,
                const float* __restrict__ u1, const float* __restrict__ p1,
                const float* __restrict__ w2, const float* __restrict__ b2,
                const float* __restrict__ u2, const float* __restrict__ p2,
                const float* __restrict__ w3, const float* __restrict__ b3,
                const float* __restrict__ u3, const float* __restrict__ p3,
                const float* __restrict__ l1w, const float* __restrict__ l1b,
                const float* __restrict__ l2w, const float* __restrict__ l2b,
                const float* __restrict__ l3w, const float* __restrict__ l3b,
                float* __restrict__ out)
{
  const int g = blockIdx.x;
  const int tid = (int)threadIdx.x;
  const int lane = tid & 63, wv = tid >> 6;

  __shared__ Smem sm;
  float* h_lds = sm.hu.h;

  const int* esrc = eidx + (size_t)g * (2 * NEDGE);
  const int* edst = esrc + NEDGE;

  // ---- init: x = emb[ids] ----
  float x[DIM];
  if (tid < NNODE) {
    int id = x_ids[(size_t)g * NNODE + tid];
    const float4* ep = (const float4*)(emb + id * DIM);
    #pragma unroll
    for (int c4 = 0; c4 < 8; ++c4) {
      float4 v = ep[c4];
      x[c4*4+0]=v.x; x[c4*4+1]=v.y; x[c4*4+2]=v.z; x[c4*4+3]=v.w;
    }
  } else {
    #pragma unroll
    for (int c = 0; c < DIM; ++c) x[c] = 0.f;
  }
  sm.mp[tid] = (tid < NNODE) ? (short)tid : (short)-1;
  if (tid < 64) sm.eacc[tid] = 0.f;
  __syncthreads();

  int n = NNODE;
  #pragma unroll 1
  for (int layer = 0; layer < 3; ++layer) {
    const float* W  = (layer==0)? w1 : (layer==1)? w2 : w3;
    const float* Bv = (layer==0)? b1 : (layer==1)? b2 : b3;
    const float* U  = (layer==0)? u1 : (layer==1)? u2 : u3;
    const float* P  = (layer==0)? p1 : (layer==1)? p2 : p3;
    const int k     = (layer==0)? 800 : (layer==1)? 640 : 512;

    // ---- CSR build: single global edge pass, stage mapped pairs in LDS ----
    sm.cnt[tid] = 0u;
    __syncthreads();
    for (int e = tid; e < NEDGE; e += 1024) {
      int s = sm.mp[esrc[e]];
      int d = sm.mp[edst[e]];
      unsigned pk = 0xFFFFFFFFu;
      if (s >= 0 && d >= 0) {
        pk = ((unsigned)d << 16) | (unsigned)s;
        atomicAdd(&sm.cnt[d], 1u);
      }
      sm.hu.stage[e] = pk;
    }
    __syncthreads();
    unsigned cv = sm.cnt[tid];
    unsigned excl = blockExclScan(cv, sm.wsum, tid);
    unsigned total = sm.wsum[15];
    if (tid < n) sm.rowStart[tid] = excl;
    if (tid == 0) sm.rowStart[n] = total;
    sm.cnt[tid] = excl;              // cursor
    __syncthreads();
    for (int e = tid; e < NEDGE; e += 1024) {
      unsigned pk = sm.hu.stage[e];
      if (pk != 0xFFFFFFFFu) {
        unsigned d = pk >> 16;
        unsigned pos = atomicAdd(&sm.cnt[d], 1u);
        sm.csr[pos] = (unsigned short)(pk & 0xFFFFu);
      }
    }
    __syncthreads();   // stage consumed; csr complete; h region reusable

    // ---- per-node matmuls: acc = U[:,32:64] @ x ; h = relu(W x + b) ----
    float acc[DIM], hv0[16], hv1[16];
    if (tid < n) {
      #pragma unroll
      for (int r = 0; r < DIM; ++r) {
        float s = 0.f;
        #pragma unroll
        for (int c = 0; c < DIM; ++c) s += U[r*64 + 32 + c] * x[c];
        acc[r] = s;
      }
      #pragma unroll
      for (int r = 0; r < 16; ++r) {
        float s = Bv[r];
        #pragma unroll
        for (int c = 0; c < DIM; ++c) s += W[r*32 + c] * x[c];
        hv0[r] = fmaxf(s, 0.f);
      }
      #pragma unroll
      for (int r = 0; r < 16; ++r) {
        float s = Bv[16 + r];
        #pragma unroll
        for (int c = 0; c < DIM; ++c) s += W[(16+r)*32 + c] * x[c];
        hv1[r] = fmaxf(s, 0.f);
      }
      store16(h_lds + tid * HSTR, hv0);
    }
    __syncthreads();   // h half0 visible

    // ---- aggregate half0 (self-loop = init with own hv0) ----
    if (tid < n) {
      unsigned beg = sm.rowStart[tid], end = sm.rowStart[tid+1];
      for (unsigned e = beg; e < end; ++e) {
        int s = sm.csr[e];
        max16(hv0, h_lds + s * HSTR);
      }
      #pragma unroll
      for (int r = 0; r < DIM; ++r) {
        float s = acc[r];
        #pragma unroll
        for (int c = 0; c < 16; ++c) s += U[r*64 + c] * hv0[c];
        acc[r] = s;
      }
    }
    __syncthreads();
    if (tid < n) store16(h_lds + tid * HSTR, hv1);
    __syncthreads();
    // ---- aggregate half1 + finish out = relu(U @ [aggr|x]) ----
    if (tid < n) {
      unsigned beg = sm.rowStart[tid], end = sm.rowStart[tid+1];
      for (unsigned e = beg; e < end; ++e) {
        int s = sm.csr[e];
        max16(hv1, h_lds + s * HSTR);
      }
      #pragma unroll
      for (int r = 0; r < DIM; ++r) {
        float s = acc[r];
        #pragma unroll
        for (int c = 0; c < 16; ++c) s += U[r*64 + 16 + c] * hv1[c];
        x[r] = fmaxf(s, 0.f);   // new x
      }
    }

    // ---- pool: score = tanh(x.p/||p||), exact top-k via radix select ----
    float pn = 0.f;
    #pragma unroll
    for (int c = 0; c < DIM; ++c) pn += P[c] * P[c];
    pn = sqrtf(pn);
    unsigned key = 0xFFFFFFFFu;
    if (tid < n) {
      float dp = 0.f;
      #pragma unroll
      for (int c = 0; c < DIM; ++c) dp += x[c] * P[c];
      float sc = tanhf(dp / pn);
      sm.score[tid] = sc;
      key = ~monof(sc);   // ascending key == descending score
    }
    bool cand = (tid < n);
    bool sel = false;
    unsigned target = (unsigned)k;
    #pragma unroll 1
    for (int pass = 0; pass < 4; ++pass) {
      for (int i = tid; i < 257; i += 1024) sm.hist[i] = 0u;
      __syncthreads();
      unsigned dig = (key >> (24 - 8*pass)) & 255u;
      if (cand) atomicAdd(&sm.hist[dig], 1u);
      __syncthreads();
      if (tid < 64) {  // wave0: exclusive scan of 256 buckets
        unsigned a0s = sm.hist[tid*4], a1s = sm.hist[tid*4+1], a2s = sm.hist[tid*4+2], a3s = sm.hist[tid*4+3];
        unsigned s1 = a0s+a1s, s2v = s1+a2s, s3 = s2v+a3s;
        unsigned tot = s3;
        #pragma unroll
        for (int d = 1; d < 64; d <<= 1) {
          unsigned t = __shfl_up(tot, d, 64);
          if (lane >= d) tot += t;
        }
        unsigned base = tot - s3;
        sm.hist[tid*4] = base; sm.hist[tid*4+1] = base+a0s; sm.hist[tid*4+2] = base+s1; sm.hist[tid*4+3] = base+s2v;
        if (tid == 63) sm.hist[256] = tot;
      }
      __syncthreads();
      if (cand) {
        unsigned lo = sm.hist[dig], hi = sm.hist[dig+1];
        if (hi <= target)      { sel = true;  cand = false; }
        else if (lo >= target) { cand = false; }
        else                   { target -= lo; }
      }
      __syncthreads();
    }
    // tie resolution among pivot-equal candidates: smallest indices win
    unsigned trank = blockExclScan(cand ? 1u : 0u, sm.wsum, tid);
    if (cand && trank < target) sel = true;
    unsigned pos = blockExclScan(sel ? 1u : 0u, sm.wsum, tid);
    sm.nidx[tid] = -1;
    __syncthreads();
    if (sel) { sm.nidx[tid] = (short)pos; sm.perm[pos] = (unsigned short)tid; }
    __syncthreads();

    // ---- gather xn = x[perm]*vals through LDS (2 halves) ----
    if (tid < n) store16(h_lds + tid * HSTR, x);
    __syncthreads();
    float nx0[16]; float val = 0.f; int pj = 0;
    if (tid < k) {
      pj = sm.perm[tid];
      val = sm.score[pj];
      loadscale16(nx0, h_lds + pj * HSTR, val);
    }
    __syncthreads();
    if (tid < n) {
      float4* hp = (float4*)(h_lds + tid * HSTR);
      hp[0] = make_float4(x[16],x[17],x[18],x[19]);
      hp[1] = make_float4(x[20],x[21],x[22],x[23]);
      hp[2] = make_float4(x[24],x[25],x[26],x[27]);
      hp[3] = make_float4(x[28],x[29],x[30],x[31]);
    }
    __syncthreads();
    if (tid < k) {
      float nx1[16];
      loadscale16(nx1, h_lds + pj * HSTR, val);
      #pragma unroll
      for (int c = 0; c < 16; ++c) { x[c] = nx0[c]; x[16+c] = nx1[c]; }
    } else {
      #pragma unroll
      for (int c = 0; c < DIM; ++c) x[c] = 0.f;
    }
    // compose orig->current map
    {
      short m0 = sm.mp[tid];
      if (m0 >= 0) sm.mp[tid] = sm.nidx[m0];
    }
    n = k;

    // ---- readout: gmp || gap on pooled x, accumulate into eacc ----
    #pragma unroll
    for (int ch = 0; ch < 2; ++ch) {
      float mx[16], smv[16];
      #pragma unroll
      for (int f = 0; f < 16; ++f) {
        float v = x[ch*16+f];
        bool act = (tid < n);
        mx[f] = act ? v : -__builtin_inff();
        smv[f] = act ? v : 0.f;
      }
      #pragma unroll
      for (int d = 32; d >= 1; d >>= 1) {
        #pragma unroll
        for (int f = 0; f < 16; ++f) {
          mx[f] = fmaxf(mx[f], __shfl_xor(mx[f], d, 64));
          smv[f] += __shfl_xor(smv[f], d, 64);
        }
      }
      if (lane == 0) {
        #pragma unroll
        for (int f = 0; f < 16; ++f) {
          sm.redm[wv*32 + ch*16 + f] = mx[f];
          sm.reds[wv*32 + ch*16 + f] = smv[f];
        }
      }
    }
    __syncthreads();
    if (tid < 32) {
      float rm = -__builtin_inff(), rs = 0.f;
      #pragma unroll
      for (int w_ = 0; w_ < 16; ++w_) {
        rm = fmaxf(rm, sm.redm[w_*32 + tid]);
        rs += sm.reds[w_*32 + tid];
      }
      sm.eacc[tid] += rm;
      sm.eacc[32 + tid] += rs / (float)n;
    }
    __syncthreads();
  }

  // ---- MLP head ----
  if (tid < 32) {
    float v = l1b[tid];
    #pragma unroll
    for (int c = 0; c < 64; ++c) v += l1w[tid*64 + c] * sm.eacc[c];
    sm.hbuf[tid] = fmaxf(v, 0.f);
  }
  __syncthreads();
  if (tid < 16) {
    float v = l2b[tid];
    #pragma unroll
    for (int c = 0; c < 32; ++c) v += l2w[tid*32 + c] * sm.hbuf[c];
    sm.hbuf[32 + tid] = fmaxf(v, 0.f);
  }
  __syncthreads();
  if (tid == 0) {
    float v = l3b[0];
    #pragma unroll
    for (int c = 0; c < 16; ++c) v += l3w[c] * sm.hbuf[32 + c];
    out[g] = 1.f / (1.f + expf(-v));
  }
  if (tid < 64) out[NGRAPH + (size_t)g*64 + tid] = sm.eacc[tid];
}

extern "C" void kernel_launch(void* const* d_in, const int* in_sizes, int n_in,
                              void* d_out, int out_size, void* d_ws, size_t ws_size,
                              hipStream_t stream) {
  (void)in_sizes; (void)n_in; (void)d_ws; (void)ws_size; (void)out_size;
  const int*   x_ids = (const int*)d_in[0];
  const int*   eidx  = (const int*)d_in[1];
  const float* emb   = (const float*)d_in[2];
  const float* w1 = (const float*)d_in[3],  *b1 = (const float*)d_in[4];
  const float* u1 = (const float*)d_in[5],  *p1 = (const float*)d_in[6];
  const float* w2 = (const float*)d_in[7],  *b2 = (const float*)d_in[8];
  const float* u2 = (const float*)d_in[9],  *p2 = (const float*)d_in[10];
  const float* w3 = (const float*)d_in[11], *b3 = (const float*)d_in[12];
  const float* u3 = (const float*)d_in[13], *p3 = (const float*)d_in[14];
  const float* l1w = (const float*)d_in[15], *l1b = (const float*)d_in[16];
  const float* l2w = (const float*)d_in[17], *l2b = (const float*)d_in[18];
  const float* l3w = (const float*)d_in[19], *l3b = (const float*)d_in[20];
  float* out = (float*)d_out;

  gnn_topk_kernel<<<dim3(NGRAPH), dim3(1024), 0, stream>>>(
      x_ids, eidx, emb,
      w1, b1, u1, p1, w2, b2, u2, p2, w3, b3, u3, p3,
      l1w, l1b, l2w, l2b, l3w, l3b, out);
}

// Round 6
// 275.187 us; speedup vs baseline: 1.4029x; 1.2489x over previous
//
#include <hip/hip_runtime.h>

#define NGRAPH 256
#define NNODE  1000
#define NEDGE  16000
#define DIM    32
#define HSTR   20   // h row stride in floats (80B: 16B-aligned, spreads banks)

__device__ __forceinline__ unsigned monof(float f) {
  unsigned b = __float_as_uint(f);
  return (b & 0x80000000u) ? ~b : (b | 0x80000000u);
}

__device__ __forceinline__ float4 f4max(float4 a, float4 b) {
  return make_float4(fmaxf(a.x,b.x), fmaxf(a.y,b.y), fmaxf(a.z,b.z), fmaxf(a.w,b.w));
}
__device__ __forceinline__ float4 f4relu(float4 a) {
  return make_float4(fmaxf(a.x,0.f), fmaxf(a.y,0.f), fmaxf(a.z,0.f), fmaxf(a.w,0.f));
}
__device__ __forceinline__ float4 f4scale(float4 a, float s) {
  return make_float4(a.x*s, a.y*s, a.z*s, a.w*s);
}
__device__ __forceinline__ float4 f4add(float4 a, float4 b) {
  return make_float4(a.x+b.x, a.y+b.y, a.z+b.z, a.w+b.w);
}
__device__ __forceinline__ float dot4(float4 a, float4 b) {
  return a.x*b.x + a.y*b.y + a.z*b.z + a.w*b.w;
}
__device__ __forceinline__ float4 shfl4(float4 v, int m) {
  return make_float4(__shfl_xor(v.x,m,64), __shfl_xor(v.y,m,64),
                     __shfl_xor(v.z,m,64), __shfl_xor(v.w,m,64));
}
__device__ __forceinline__ float4 lds4(const float* p) { return *(const float4*)p; }

struct __align__(16) Smem {
  union { float h[NNODE * HSTR]; unsigned stage[NEDGE]; } hu;  // 80000 B
  unsigned short csr[NEDGE];      // 32000
  unsigned rowStart[1004];        // 4016 (padded for 16B alignment)
  unsigned cnt[1024];             // 4096
  float score[1024];              // 4096
  unsigned short perm[1024];      // 2048
  short nidx[1024];               // 2048
  short mp[1024];                 // 2048
  unsigned hist[260];             // 1040 (257 used, padded)
  unsigned wsum[16];              // 64
  float redm[512];                // 2048
  float reds[512];                // 2048
  float eacc[64];                 // 256
  float hbuf[48];                 // 192  => 136000 B total
};

// exclusive block scan over 1024 threads; leaves total in wsum[15]
__device__ __forceinline__ unsigned blockExclScan(unsigned v, unsigned* wsum, int tid) {
  __syncthreads();
  int lane = tid & 63, w = tid >> 6;
  unsigned x = v;
  #pragma unroll
  for (int d = 1; d < 64; d <<= 1) {
    unsigned t = __shfl_up(x, d, 64);
    if (lane >= d) x += t;
  }
  if (lane == 63) wsum[w] = x;
  __syncthreads();
  if (w == 0) {
    unsigned s = (lane < 16) ? wsum[lane] : 0u;
    #pragma unroll
    for (int d = 1; d < 16; d <<= 1) {
      unsigned t = __shfl_up(s, d, 64);
      if (lane >= d) s += t;
    }
    if (lane < 16) wsum[lane] = s;
  }
  __syncthreads();
  unsigned base = (w > 0) ? wsum[w - 1] : 0u;
  return base + x - v;
}

// dot of 8 float4 weight words against x0..x7 (x* are locals in scope)
#define XDOT(P4, R, S, O) ( dot4((P4)[(R)*(S)+(O)  ], x0) + dot4((P4)[(R)*(S)+(O)+1], x1) \
                          + dot4((P4)[(R)*(S)+(O)+2], x2) + dot4((P4)[(R)*(S)+(O)+3], x3) \
                          + dot4((P4)[(R)*(S)+(O)+4], x4) + dot4((P4)[(R)*(S)+(O)+5], x5) \
                          + dot4((P4)[(R)*(S)+(O)+6], x6) + dot4((P4)[(R)*(S)+(O)+7], x7) )
// dot of 4 float4 U words against h0..h3 (aggregated half)
#define GDOT(R, O) ( dot4(U4[(R)*16+(O)  ], h0) + dot4(U4[(R)*16+(O)+1], h1) \
                   + dot4(U4[(R)*16+(O)+2], h2) + dot4(U4[(R)*16+(O)+3], h3) )
#define ACC4(v, R)    v.x  = XDOT(U4,(R),16,8); v.y  = XDOT(U4,(R)+1,16,8); v.z  = XDOT(U4,(R)+2,16,8); v.w  = XDOT(U4,(R)+3,16,8);
#define ACC4ADD(v, R, O) v.x += GDOT((R),(O)); v.y += GDOT((R)+1,(O)); v.z += GDOT((R)+2,(O)); v.w += GDOT((R)+3,(O));
#define HV4(v, R)     v.x = fmaxf(Bv[(R)]+XDOT(W4,(R),8,0),0.f); v.y = fmaxf(Bv[(R)+1]+XDOT(W4,(R)+1,8,0),0.f); \
                      v.z = fmaxf(Bv[(R)+2]+XDOT(W4,(R)+2,8,0),0.f); v.w = fmaxf(Bv[(R)+3]+XDOT(W4,(R)+3,8,0),0.f);
#define REDCH(v, OFF) do { \
  float4 mx = act ? (v) : make_float4(-__builtin_inff(),-__builtin_inff(),-__builtin_inff(),-__builtin_inff()); \
  float4 sv = act ? (v) : make_float4(0.f,0.f,0.f,0.f); \
  mx = f4max(mx, shfl4(mx,32)); sv = f4add(sv, shfl4(sv,32)); \
  mx = f4max(mx, shfl4(mx,16)); sv = f4add(sv, shfl4(sv,16)); \
  mx = f4max(mx, shfl4(mx, 8)); sv = f4add(sv, shfl4(sv, 8)); \
  mx = f4max(mx, shfl4(mx, 4)); sv = f4add(sv, shfl4(sv, 4)); \
  mx = f4max(mx, shfl4(mx, 2)); sv = f4add(sv, shfl4(sv, 2)); \
  mx = f4max(mx, shfl4(mx, 1)); sv = f4add(sv, shfl4(sv, 1)); \
  if (lane == 0) { *((float4*)(sm.redm + wv*32 + (OFF))) = mx; *((float4*)(sm.reds + wv*32 + (OFF))) = sv; } \
} while (0)

extern "C" __global__ void
__attribute__((amdgpu_flat_work_group_size(1024,1024)))
__attribute__((amdgpu_waves_per_eu(4,4)))
gnn_topk_kernel(const int* __restrict__ x_ids, const int* __restrict__ eidx,
                const float* __restrict__ emb,
                const float* __restrict__ w1, const float* __restrict__ b1,
                const float* __restrict__ u1, const float* __restrict__ p1,
                const float* __restrict__ w2, const float* __restrict__ b2,
                const float* __restrict__ u2, const float* __restrict__ p2,
                const float* __restrict__ w3, const float* __restrict__ b3,
                const float* __restrict__ u3, const float* __restrict__ p3,
                const float* __restrict__ l1w, const float* __restrict__ l1b,
                const float* __restrict__ l2w, const float* __restrict__ l2b,
                const float* __restrict__ l3w, const float* __restrict__ l3b,
                float* __restrict__ out)
{
  const int g = blockIdx.x;
  const int tid = (int)threadIdx.x;
  const int lane = tid & 63, wv = tid >> 6;

  __shared__ Smem sm;
  float* h_lds = sm.hu.h;

  const int* esrc = eidx + (size_t)g * (2 * NEDGE);
  const int* edst = esrc + NEDGE;

  // ---- init: x = emb[ids], all state in float4 VALUES (no private arrays) ----
  float4 x0,x1,x2,x3,x4,x5,x6,x7;
  if (tid < NNODE) {
    int id = x_ids[(size_t)g * NNODE + tid];
    const float4* ep = (const float4*)(emb + id * DIM);
    x0=ep[0]; x1=ep[1]; x2=ep[2]; x3=ep[3]; x4=ep[4]; x5=ep[5]; x6=ep[6]; x7=ep[7];
  } else {
    x0=x1=x2=x3=x4=x5=x6=x7=make_float4(0.f,0.f,0.f,0.f);
  }
  sm.mp[tid] = (tid < NNODE) ? (short)tid : (short)-1;
  if (tid < 64) sm.eacc[tid] = 0.f;
  __syncthreads();

  int n = NNODE;
  #pragma unroll 1
  for (int layer = 0; layer < 3; ++layer) {
    const float* W  = (layer==0)? w1 : (layer==1)? w2 : w3;
    const float* Bv = (layer==0)? b1 : (layer==1)? b2 : b3;
    const float* U  = (layer==0)? u1 : (layer==1)? u2 : u3;
    const float* P  = (layer==0)? p1 : (layer==1)? p2 : p3;
    const int k     = (layer==0)? 800 : (layer==1)? 640 : 512;
    const float4* W4 = (const float4*)W;
    const float4* U4 = (const float4*)U;

    // ---- CSR build: single global edge pass, stage mapped pairs in LDS ----
    sm.cnt[tid] = 0u;
    __syncthreads();
    for (int e = tid; e < NEDGE; e += 1024) {
      int s = sm.mp[esrc[e]];
      int d = sm.mp[edst[e]];
      unsigned pk = 0xFFFFFFFFu;
      if (s >= 0 && d >= 0) {
        pk = ((unsigned)d << 16) | (unsigned)s;
        atomicAdd(&sm.cnt[d], 1u);
      }
      sm.hu.stage[e] = pk;
    }
    __syncthreads();
    unsigned cv = sm.cnt[tid];
    unsigned excl = blockExclScan(cv, sm.wsum, tid);
    unsigned total = sm.wsum[15];
    if (tid < n) sm.rowStart[tid] = excl;
    if (tid == 0) sm.rowStart[n] = total;
    sm.cnt[tid] = excl;              // cursor
    __syncthreads();
    for (int e = tid; e < NEDGE; e += 1024) {
      unsigned pk = sm.hu.stage[e];
      if (pk != 0xFFFFFFFFu) {
        unsigned d = pk >> 16;
        unsigned pos = atomicAdd(&sm.cnt[d], 1u);
        sm.csr[pos] = (unsigned short)(pk & 0xFFFFu);
      }
    }
    __syncthreads();   // stage consumed; csr complete; h region reusable

    // ---- SAGE: acc = U[:,32:64]@x ; h0..h3 = relu(W[0:16]@x+b) ----
    float4 a0,a1,a2,a3,a4,a5,a6,a7;
    float4 h0,h1,h2,h3;
    float4* hp = (float4*)(h_lds + tid * HSTR);
    if (tid < n) {
      ACC4(a0,0) ACC4(a1,4) ACC4(a2,8) ACC4(a3,12) ACC4(a4,16) ACC4(a5,20) ACC4(a6,24) ACC4(a7,28)
      HV4(h0,0) HV4(h1,4) HV4(h2,8) HV4(h3,12)
      hp[0]=h0; hp[1]=h1; hp[2]=h2; hp[3]=h3;
    }
    __syncthreads();   // h half0 visible
    if (tid < n) {
      unsigned beg = sm.rowStart[tid], end = sm.rowStart[tid+1];
      for (unsigned e = beg; e < end; ++e) {
        const float* rp = h_lds + sm.csr[e] * HSTR;
        h0 = f4max(h0, lds4(rp));   h1 = f4max(h1, lds4(rp+4));
        h2 = f4max(h2, lds4(rp+8)); h3 = f4max(h3, lds4(rp+12));
      }
      ACC4ADD(a0,0,0) ACC4ADD(a1,4,0) ACC4ADD(a2,8,0) ACC4ADD(a3,12,0)
      ACC4ADD(a4,16,0) ACC4ADD(a5,20,0) ACC4ADD(a6,24,0) ACC4ADD(a7,28,0)
    }
    __syncthreads();
    if (tid < n) {
      HV4(h0,16) HV4(h1,20) HV4(h2,24) HV4(h3,28)
      hp[0]=h0; hp[1]=h1; hp[2]=h2; hp[3]=h3;
    }
    __syncthreads();
    if (tid < n) {
      unsigned beg = sm.rowStart[tid], end = sm.rowStart[tid+1];
      for (unsigned e = beg; e < end; ++e) {
        const float* rp = h_lds + sm.csr[e] * HSTR;
        h0 = f4max(h0, lds4(rp));   h1 = f4max(h1, lds4(rp+4));
        h2 = f4max(h2, lds4(rp+8)); h3 = f4max(h3, lds4(rp+12));
      }
      ACC4ADD(a0,0,4) ACC4ADD(a1,4,4) ACC4ADD(a2,8,4) ACC4ADD(a3,12,4)
      ACC4ADD(a4,16,4) ACC4ADD(a5,20,4) ACC4ADD(a6,24,4) ACC4ADD(a7,28,4)
      x0=f4relu(a0); x1=f4relu(a1); x2=f4relu(a2); x3=f4relu(a3);
      x4=f4relu(a4); x5=f4relu(a5); x6=f4relu(a6); x7=f4relu(a7);
    }

    // ---- pool: score = tanh(x.p/||p||), exact top-k via radix select ----
    float pn = 0.f;
    for (int c = 0; c < DIM; ++c) pn += P[c] * P[c];
    pn = sqrtf(pn);
    const float4* P4 = (const float4*)P;
    unsigned key = 0xFFFFFFFFu;
    if (tid < n) {
      float dp = dot4(P4[0],x0)+dot4(P4[1],x1)+dot4(P4[2],x2)+dot4(P4[3],x3)
               + dot4(P4[4],x4)+dot4(P4[5],x5)+dot4(P4[6],x6)+dot4(P4[7],x7);
      float sc = tanhf(dp / pn);
      sm.score[tid] = sc;
      key = ~monof(sc);
    }
    bool cand = (tid < n);
    bool sel = false;
    unsigned target = (unsigned)k;
    #pragma unroll 1
    for (int pass = 0; pass < 4; ++pass) {
      for (int i = tid; i < 257; i += 1024) sm.hist[i] = 0u;
      __syncthreads();
      unsigned dig = (key >> (24 - 8*pass)) & 255u;
      if (cand) atomicAdd(&sm.hist[dig], 1u);
      __syncthreads();
      if (tid < 64) {
        unsigned q0 = sm.hist[tid*4], q1 = sm.hist[tid*4+1], q2 = sm.hist[tid*4+2], q3 = sm.hist[tid*4+3];
        unsigned s1 = q0+q1, s2v = s1+q2, s3 = s2v+q3;
        unsigned tot = s3;
        #pragma unroll
        for (int d = 1; d < 64; d <<= 1) {
          unsigned t = __shfl_up(tot, d, 64);
          if (lane >= d) tot += t;
        }
        unsigned base = tot - s3;
        sm.hist[tid*4] = base; sm.hist[tid*4+1] = base+q0; sm.hist[tid*4+2] = base+s1; sm.hist[tid*4+3] = base+s2v;
        if (tid == 63) sm.hist[256] = tot;
      }
      __syncthreads();
      if (cand) {
        unsigned lo = sm.hist[dig], hi = sm.hist[dig+1];
        if (hi <= target)      { sel = true;  cand = false; }
        else if (lo >= target) { cand = false; }
        else                   { target -= lo; }
      }
      __syncthreads();
    }
    unsigned trank = blockExclScan(cand ? 1u : 0u, sm.wsum, tid);
    if (cand && trank < target) sel = true;
    unsigned pos = blockExclScan(sel ? 1u : 0u, sm.wsum, tid);
    sm.nidx[tid] = -1;
    __syncthreads();
    if (sel) { sm.nidx[tid] = (short)pos; sm.perm[pos] = (unsigned short)tid; }
    __syncthreads();

    // ---- gather xn = x[perm]*vals through LDS (2 halves) ----
    if (tid < n) { hp[0]=x0; hp[1]=x1; hp[2]=x2; hp[3]=x3; }
    __syncthreads();
    float4 n0,n1,n2,n3; float val = 0.f; int pj = 0;
    if (tid < k) {
      pj = sm.perm[tid];
      val = sm.score[pj];
      const float* rp = h_lds + pj * HSTR;
      n0 = f4scale(lds4(rp),   val); n1 = f4scale(lds4(rp+4),  val);
      n2 = f4scale(lds4(rp+8), val); n3 = f4scale(lds4(rp+12), val);
    }
    __syncthreads();
    if (tid < n) { hp[0]=x4; hp[1]=x5; hp[2]=x6; hp[3]=x7; }
    __syncthreads();
    if (tid < k) {
      const float* rp = h_lds + pj * HSTR;
      x4 = f4scale(lds4(rp),   val); x5 = f4scale(lds4(rp+4),  val);
      x6 = f4scale(lds4(rp+8), val); x7 = f4scale(lds4(rp+12), val);
      x0 = n0; x1 = n1; x2 = n2; x3 = n3;
    } else {
      x0=x1=x2=x3=x4=x5=x6=x7=make_float4(0.f,0.f,0.f,0.f);
    }
    // compose orig->current map
    {
      short m0 = sm.mp[tid];
      if (m0 >= 0) sm.mp[tid] = sm.nidx[m0];
    }
    n = k;

    // ---- readout: gmp || gap on pooled x, accumulate into eacc ----
    {
      bool act = (tid < n);
      REDCH(x0, 0); REDCH(x1, 4); REDCH(x2, 8);  REDCH(x3, 12);
      REDCH(x4,16); REDCH(x5,20); REDCH(x6,24);  REDCH(x7,28);
    }
    __syncthreads();
    if (tid < 32) {
      float rm = -__builtin_inff(), rs = 0.f;
      #pragma unroll
      for (int w_ = 0; w_ < 16; ++w_) {
        rm = fmaxf(rm, sm.redm[w_*32 + tid]);
        rs += sm.reds[w_*32 + tid];
      }
      sm.eacc[tid] += rm;
      sm.eacc[32 + tid] += rs / (float)n;
    }
    __syncthreads();
  }

  // ---- MLP head ----
  if (tid < 32) {
    float v = l1b[tid];
    #pragma unroll
    for (int c = 0; c < 64; ++c) v += l1w[tid*64 + c] * sm.eacc[c];
    sm.hbuf[tid] = fmaxf(v, 0.f);
  }
  __syncthreads();
  if (tid < 16) {
    float v = l2b[tid];
    #pragma unroll
    for (int c = 0; c < 32; ++c) v += l2w[tid*32 + c] * sm.hbuf[c];
    sm.hbuf[32 + tid] = fmaxf(v, 0.f);
  }
  __syncthreads();
  if (tid == 0) {
    float v = l3b[0];
    #pragma unroll
    for (int c = 0; c < 16; ++c) v += l3w[c] * sm.hbuf[32 + c];
    out[g] = 1.f / (1.f + expf(-v));
  }
  if (tid < 64) out[NGRAPH + (size_t)g*64 + tid] = sm.eacc[tid];
}

extern "C" void kernel_launch(void* const* d_in, const int* in_sizes, int n_in,
                              void* d_out, int out_size, void* d_ws, size_t ws_size,
                              hipStream_t stream) {
  (void)in_sizes; (void)n_in; (void)d_ws; (void)ws_size; (void)out_size;
  const int*   x_ids = (const int*)d_in[0];
  const int*   eidx  = (const int*)d_in[1];
  const float* emb   = (const float*)d_in[2];
  const float* w1 = (const float*)d_in[3],  *b1 = (const float*)d_in[4];
  const float* u1 = (const float*)d_in[5],  *p1 = (const float*)d_in[6];
  const float* w2 = (const float*)d_in[7],  *b2 = (const float*)d_in[8];
  const float* u2 = (const float*)d_in[9],  *p2 = (const float*)d_in[10];
  const float* w3 = (const float*)d_in[11], *b3 = (const float*)d_in[12];
  const float* u3 = (const float*)d_in[13], *p3 = (const float*)d_in[14];
  const float* l1w = (const float*)d_in[15], *l1b = (const float*)d_in[16];
  const float* l2w = (const float*)d_in[17], *l2b = (const float*)d_in[18];
  const float* l3w = (const float*)d_in[19], *l3b = (const float*)d_in[20];
  float* out = (float*)d_out;

  gnn_topk_kernel<<<dim3(NGRAPH), dim3(1024), 0, stream>>>(
      x_ids, eidx, emb,
      w1, b1, u1, p1, w2, b2, u2, p2, w3, b3, u3, p3,
      l1w, l1b, l2w, l2b, l3w, l3b, out);
}